// Round 1
// baseline (62768.488 us; speedup 1.0000x reference)
//
#include <hip/hip_runtime.h>
#include <stdint.h>

// ---------------------------------------------------------------------------
// Bidirectional 2-layer LSTM, persistent-wave scan design.
//   B=32, T=2048, D=256, H=256, gates G=4H=1024 (i,f,g,o PyTorch order).
// Per direction ("scan"): 8 WGs x 256 thr = 32 waves. Wave owns 16 hidden
// units x 4 gates (64 gate cols) x 16 batch rows. Weight slice resident in
// VGPRs as MFMA B-fragments (bf16). Input GEMM fused (computed during the
// wait bubble). Cross-wave h broadcast via global bf16 buffer + per-wave
// monotonic flags (device-scope atomics, parity double buffer).
// MFMA: v_mfma_f32_16x16x32_bf16.
//   A-frag: lane holds A[m=lane&15][k=(lane>>4)*8 + j], j=0..7
//   B-frag: lane holds B[k=(lane>>4)*8 + j][n=lane&15]
//   C/D   : lane holds C[row=(lane>>4)*4 + reg][col=lane&15]
// ---------------------------------------------------------------------------

#define Bn 32
#define Tn 2048
#define Hn 256

typedef short short8 __attribute__((ext_vector_type(8)));
typedef float f32x4 __attribute__((ext_vector_type(4)));

__device__ inline unsigned short f2b(float f) {  // fp32 -> bf16 RNE
  union { float f; unsigned u; } v; v.f = f;
  unsigned r = v.u + 0x7fffu + ((v.u >> 16) & 1u);
  return (unsigned short)(r >> 16);
}
__device__ inline float sigx(float x) {
  return __builtin_amdgcn_rcpf(1.f + __expf(-x));
}
__device__ inline float tanhx(float x) {
  return 2.f * __builtin_amdgcn_rcpf(1.f + __expf(-2.f * x)) - 1.f;
}

// DX: input width (256 fp32 x for layer0, 512 bf16 h0 for layer1)
template <int DX, bool LAYER1>
__global__ __launch_bounds__(256, 1) void lstm_scan(
    const void* __restrict__ xin_,
    const float* __restrict__ Wih_f, const float* __restrict__ Whh_f,
    const float* __restrict__ bias_f,
    const float* __restrict__ Wih_r, const float* __restrict__ Whh_r,
    const float* __restrict__ bias_r,
    unsigned short* __restrict__ hbuf,  // [2 scans][2 slots][32][256] bf16
    int* __restrict__ flags,            // [2 scans][32]
    unsigned short* __restrict__ h0out, // layerA out [B,T,512] bf16
    float* __restrict__ dout)           // layerB out [B,T,512] f32
{
  const int bid = blockIdx.x;
  const int scan = bid & 7;           // blockIdx%8 -> likely XCD id (perf only)
  if (scan >= 2) return;              // 16 working blocks of 64
  const int wg   = bid >> 3;          // 0..7
  const int tid  = threadIdx.x;
  const int wave = tid >> 6;
  const int lane = tid & 63;
  const int slot = wg * 4 + wave;     // 0..31 wave slot within scan
  const int cg   = slot >> 1;         // col-group: 16 units
  const int mh   = slot & 1;          // batch half
  const int l15  = lane & 15;
  const int quad = lane >> 4;

  const float* Wih  = scan ? Wih_r  : Wih_f;
  const float* Whh  = scan ? Whh_r  : Whh_f;
  const float* bias = scan ? bias_r : bias_f;

  constexpr int KIT = (DX + Hn) / 32;  // total k-iterations
  constexpr int KIX = DX / 32;         // input-part k-iterations
  constexpr int KIH = Hn / 32;         // recurrent-part k-iterations (8)

  const int U = cg * 16 + l15;         // owned hidden-unit column (0..255)

  // ---- load resident B-fragments (bf16) ----
  short8 bf[KIT][4];
#pragma unroll
  for (int ki = 0; ki < KIT; ++ki) {
#pragma unroll
    for (int g = 0; g < 4; ++g) {
      const int row = g * Hn + U;     // gate-major rows in W
      const float* src;
      if (ki * 32 < DX) src = Wih + (size_t)row * DX + ki * 32 + quad * 8;
      else              src = Whh + (size_t)row * Hn + (ki * 32 - DX) + quad * 8;
      short8 v;
#pragma unroll
      for (int j = 0; j < 8; ++j) v[j] = (short)f2b(src[j]);
      bf[ki][g] = v;
    }
  }
  float bias4[4];
#pragma unroll
  for (int g = 0; g < 4; ++g) bias4[g] = bias[g * Hn + U];

  unsigned short* myhb = hbuf + (size_t)scan * (2 * Bn * Hn);
  int* myflags = flags + scan * 32;

  const int mrow_a = mh * 16 + l15;   // A-fragment batch row for loads

  float c_st[4] = {0.f, 0.f, 0.f, 0.f};

  for (int s = 0; s < Tn; ++s) {
    const int t = scan ? (Tn - 1 - s) : s;

    f32x4 acc[4];
#pragma unroll
    for (int g = 0; g < 4; ++g) {
      f32x4 ai = {bias4[g], bias4[g], bias4[g], bias4[g]};
      acc[g] = ai;
    }

    // ---- input projection: independent of other waves (fills sync bubble)
    if constexpr (!LAYER1) {
      const float* xb = (const float*)xin_ + ((size_t)mrow_a * Tn + t) * DX + quad * 8;
#pragma unroll
      for (int ki = 0; ki < KIX; ++ki) {
        f32x4 a0 = *(const f32x4*)(xb + ki * 32);
        f32x4 a1 = *(const f32x4*)(xb + ki * 32 + 4);
        short8 af;
#pragma unroll
        for (int j = 0; j < 4; ++j) { af[j] = (short)f2b(a0[j]); af[4 + j] = (short)f2b(a1[j]); }
#pragma unroll
        for (int g = 0; g < 4; ++g)
          acc[g] = __builtin_amdgcn_mfma_f32_16x16x32_bf16(af, bf[ki][g], acc[g], 0, 0, 0);
      }
    } else {
      const unsigned short* xb = (const unsigned short*)xin_ + ((size_t)mrow_a * Tn + t) * DX + quad * 8;
#pragma unroll
      for (int ki = 0; ki < KIX; ++ki) {
        short8 af = *(const short8*)(xb + ki * 32);
#pragma unroll
        for (int g = 0; g < 4; ++g)
          acc[g] = __builtin_amdgcn_mfma_f32_16x16x32_bf16(af, bf[ki][g], acc[g], 0, 0, 0);
      }
    }

    // ---- recurrent part: wait for h_{s-1} from all 32 waves of this scan
    if (s > 0) {
      const int target = s;  // flag==s means that wave finished step s-1
      for (;;) {
        int v = (lane < 32)
                  ? __hip_atomic_load(&myflags[lane], __ATOMIC_RELAXED, __HIP_MEMORY_SCOPE_AGENT)
                  : target;
        if (__all(v >= target)) break;
      }
      __threadfence();  // acquire: make remote h stores visible

      const unsigned short* hb =
          myhb + ((size_t)((s - 1) & 1) * Bn + mrow_a) * Hn + quad * 8;
#pragma unroll
      for (int ki = 0; ki < KIH; ++ki) {
        short8 af = *(const short8*)(hb + ki * 32);
#pragma unroll
        for (int g = 0; g < 4; ++g)
          acc[g] = __builtin_amdgcn_mfma_f32_16x16x32_bf16(af, bf[KIX + ki][g], acc[g], 0, 0, 0);
      }
    }

    // ---- gates + state update + outputs (C-layout rows)
    unsigned short* hwr = myhb + (size_t)(s & 1) * Bn * Hn;
#pragma unroll
    for (int r = 0; r < 4; ++r) {
      const int m = mh * 16 + quad * 4 + r;
      float pi = acc[0][r], pf = acc[1][r], pg = acc[2][r], po = acc[3][r];
      float ig = sigx(pi), fg = sigx(pf), gg = tanhx(pg), og = sigx(po);
      float cv = fg * c_st[r] + ig * gg;
      c_st[r] = cv;
      float hv = og * tanhx(cv);
      unsigned short hb16 = f2b(hv);
      hwr[(size_t)m * Hn + U] = hb16;
      if constexpr (!LAYER1) {
        h0out[((size_t)m * Tn + t) * (2 * Hn) + scan * Hn + U] = hb16;
      } else {
        dout[((size_t)m * Tn + t) * (2 * Hn) + scan * Hn + U] = hv;
      }
    }

    __threadfence();  // release: h stores globally visible before flag
    if (lane == 0)
      __hip_atomic_store(&myflags[slot], s + 1, __ATOMIC_RELAXED, __HIP_MEMORY_SCOPE_AGENT);
  }
}

extern "C" void kernel_launch(void* const* d_in, const int* in_sizes, int n_in,
                              void* d_out, int out_size, void* d_ws, size_t ws_size,
                              hipStream_t stream) {
  (void)in_sizes; (void)n_in; (void)out_size; (void)ws_size;
  const float* x      = (const float*)d_in[0];
  const float* Wih_f0 = (const float*)d_in[1];
  const float* Whh_f0 = (const float*)d_in[2];
  const float* b_f0   = (const float*)d_in[3];
  const float* Wih_r0 = (const float*)d_in[4];
  const float* Whh_r0 = (const float*)d_in[5];
  const float* b_r0   = (const float*)d_in[6];
  const float* Wih_f1 = (const float*)d_in[7];
  const float* Whh_f1 = (const float*)d_in[8];
  const float* b_f1   = (const float*)d_in[9];
  const float* Wih_r1 = (const float*)d_in[10];
  const float* Whh_r1 = (const float*)d_in[11];
  const float* b_r1   = (const float*)d_in[12];

  char* ws = (char*)d_ws;
  unsigned short* h0out = (unsigned short*)ws;                   // 67,108,864 B
  size_t off = (size_t)Bn * Tn * (2 * Hn) * sizeof(unsigned short);
  unsigned short* hbufA = (unsigned short*)(ws + off); off += 2 * 2 * Bn * Hn * 2;
  unsigned short* hbufB = (unsigned short*)(ws + off); off += 2 * 2 * Bn * Hn * 2;
  int* flagsA = (int*)(ws + off); off += 256;
  int* flagsB = (int*)(ws + off); off += 256;

  // flags must start at 0 every call (ws is poisoned 0xAA). flagsA+flagsB contiguous.
  hipMemsetAsync(flagsA, 0, 512, stream);

  dim3 grid(64), block(256);
  lstm_scan<256, false><<<grid, block, 0, stream>>>(
      (const void*)x, Wih_f0, Whh_f0, b_f0, Wih_r0, Whh_r0, b_r0,
      hbufA, flagsA, h0out, (float*)nullptr);
  lstm_scan<512, true><<<grid, block, 0, stream>>>(
      (const void*)h0out, Wih_f1, Whh_f1, b_f1, Wih_r1, Whh_r1, b_r1,
      hbufB, flagsB, (unsigned short*)nullptr, (float*)d_out);
}

// Round 2
// 16536.963 us; speedup vs baseline: 3.7956x; 3.7956x over previous
//
#include <hip/hip_runtime.h>
#include <stdint.h>

// ---------------------------------------------------------------------------
// Bidirectional 2-layer LSTM. Two-phase per layer:
//  Phase A (parallel): xg[scan][t][m][4H] = x_t . W_ih^T + b   (bf16, MFMA GEMM)
//  Phase B (scan): persistent waves, W_hh resident in VGPRs (128 regs, no spill),
//    per-step h broadcast via RELAXED agent-scope atomics (sc-bit, coherent-point)
//    ordered by bare s_waitcnt vmcnt(0) -- NO threadfence (no buffer_wbl2/inv).
// Per scan: 8 WGs x 4 waves; wave owns 16 units x 4 gates x 16 batch rows.
// MFMA 16x16x32 bf16:  A: lane=(m=lane&15, k=quad*8+j)  B: (k=quad*8+j, n=lane&15)
//                      C/D: (row=quad*4+reg, col=lane&15)
// ---------------------------------------------------------------------------

#define Bn 32
#define Tn 2048
#define Hn 256

typedef short short8 __attribute__((ext_vector_type(8)));
typedef float f32x4 __attribute__((ext_vector_type(4)));

__device__ inline unsigned short f2b(float f) {  // fp32 -> bf16 RNE
  union { float f; unsigned u; } v; v.f = f;
  unsigned r = v.u + 0x7fffu + ((v.u >> 16) & 1u);
  return (unsigned short)(r >> 16);
}
__device__ inline float b2f(unsigned short b) {
  union { unsigned u; float f; } v; v.u = ((unsigned)b) << 16;
  return v.f;
}
__device__ inline float sigx(float x) {
  return __builtin_amdgcn_rcpf(1.f + __expf(-x));
}
__device__ inline float tanhx(float x) {
  return 2.f * __builtin_amdgcn_rcpf(1.f + __expf(-2.f * x)) - 1.f;
}

// ---------------- Phase A: xg = A . W^T + b  ------------------------------
// A: [B*T, K] (fp32 x if AF32 else bf16 h0out). Output xg bf16 [2][T][B][1024].
// Wave owns a 32-gate stripe (resident B-frags, <=128 VGPR) x 16 m-tiles.
// 4 waves of a block share the m-chunk (L1 reuse of A), different stripes.
template <int K, bool AF32>
__global__ __launch_bounds__(256, 2) void xg_gemm(
    const void* __restrict__ Ain,
    const float* __restrict__ Wf, const float* __restrict__ bf_,
    const float* __restrict__ Wr, const float* __restrict__ br_,
    unsigned short* __restrict__ xg) {
  constexpr int KI = K / 32;
  const int bid = blockIdx.x;
  const int scan = bid & 1;
  const int sgrp = (bid >> 1) & 7;
  const int mchunk = bid >> 4;           // 0..255
  const int wave = threadIdx.x >> 6;
  const int lane = threadIdx.x & 63;
  const int l15 = lane & 15, quad = lane >> 4;
  const int stripe = sgrp * 4 + wave;    // 0..31 -> 32 gate-cols each
  const int gi0 = stripe * 32;

  const float* W = scan ? Wr : Wf;
  const float* bias = scan ? br_ : bf_;

  short8 bfr[KI][2];
  float bias2[2];
#pragma unroll
  for (int sub = 0; sub < 2; ++sub) {
    const int gi = gi0 + sub * 16 + l15;
    bias2[sub] = bias[gi];
#pragma unroll
    for (int ki = 0; ki < KI; ++ki) {
      const float* src = W + (size_t)gi * K + ki * 32 + quad * 8;
      short8 v;
#pragma unroll
      for (int j = 0; j < 8; ++j) v[j] = (short)f2b(src[j]);
      bfr[ki][sub] = v;
    }
  }

  const size_t scan_off = (size_t)scan << 26;  // T*B*1024 elements
#pragma unroll 1
  for (int mt0 = 0; mt0 < 16; ++mt0) {
    const int mt = mchunk * 16 + mt0;
    const size_t row = (size_t)mt * 16 + l15;
    f32x4 acc[2];
#pragma unroll
    for (int sub = 0; sub < 2; ++sub) {
      f32x4 bi = {bias2[sub], bias2[sub], bias2[sub], bias2[sub]};
      acc[sub] = bi;
    }
#pragma unroll
    for (int ki = 0; ki < KI; ++ki) {
      short8 af;
      if constexpr (AF32) {
        const float* ap = (const float*)Ain + row * K + ki * 32 + quad * 8;
        f32x4 a0 = *(const f32x4*)ap;
        f32x4 a1 = *(const f32x4*)(ap + 4);
#pragma unroll
        for (int j = 0; j < 4; ++j) { af[j] = (short)f2b(a0[j]); af[4 + j] = (short)f2b(a1[j]); }
      } else {
        const unsigned short* ap = (const unsigned short*)Ain + row * K + ki * 32 + quad * 8;
        af = *(const short8*)ap;
      }
#pragma unroll
      for (int sub = 0; sub < 2; ++sub)
        acc[sub] = __builtin_amdgcn_mfma_f32_16x16x32_bf16(af, bfr[ki][sub], acc[sub], 0, 0, 0);
    }
#pragma unroll
    for (int sub = 0; sub < 2; ++sub) {
      const int gi = gi0 + sub * 16 + l15;
#pragma unroll
      for (int r = 0; r < 4; ++r) {
        const int orow = mt * 16 + quad * 4 + r;
        const int m = orow >> 11, t = orow & 2047;
        xg[scan_off + ((size_t)t * Bn + m) * 1024 + gi] = f2b(acc[sub][r]);
      }
    }
  }
}

// ---------------- Phase B: recurrent scan ---------------------------------
template <bool LAYER1>
__global__ __launch_bounds__(256, 1) void lstm_scan(
    const unsigned short* __restrict__ xg,   // [2][T][B][1024] bf16
    const float* __restrict__ Whh_f, const float* __restrict__ Whh_r,
    unsigned short* __restrict__ hbuf,       // [2 scans][2 parity][32][256] bf16
    int* __restrict__ flags,                 // [2 scans][32]
    unsigned short* __restrict__ h0out,      // [B][T][512] bf16 (layer0)
    float* __restrict__ dout) {              // [B][T][512] f32  (layer1)
  const int bid = blockIdx.x;
  const int scan = bid & 1;
  const int wg = bid >> 1;                   // 0..7
  const int wave = threadIdx.x >> 6;
  const int lane = threadIdx.x & 63;
  const int slot = wg * 4 + wave;            // 0..31
  const int cg = slot >> 1, mh = slot & 1;
  const int l15 = lane & 15, quad = lane >> 4;
  const int U = cg * 16 + l15;               // owned hidden unit
  const int mrow = mh * 16 + l15;            // A-frag batch row

  const float* Whh = scan ? Whh_r : Whh_f;

  // resident W_hh B-fragments: 8 ki x 4 gates x 4 VGPR = 128 VGPRs
  short8 bfh[8][4];
#pragma unroll
  for (int ki = 0; ki < 8; ++ki) {
#pragma unroll
    for (int g = 0; g < 4; ++g) {
      const float* src = Whh + (size_t)(g * Hn + U) * Hn + ki * 32 + quad * 8;
      short8 v;
#pragma unroll
      for (int j = 0; j < 8; ++j) v[j] = (short)f2b(src[j]);
      bfh[ki][g] = v;
    }
  }

  unsigned short* myhb = hbuf + scan * (2 * Bn * Hn);
  int* myflags = flags + scan * 32;
  const size_t scan_off = (size_t)scan << 26;

  float c_st[4] = {0.f, 0.f, 0.f, 0.f};

  for (int s = 0; s < Tn; ++s) {
    const int t = scan ? (Tn - 1 - s) : s;

    // xg preactivations (issued before poll -> overlaps the wait)
    const unsigned short* xgp = xg + scan_off + (size_t)t * (Bn * 1024);
    f32x4 acc[4];
#pragma unroll
    for (int g = 0; g < 4; ++g) {
#pragma unroll
      for (int r = 0; r < 4; ++r) {
        const int m = mh * 16 + quad * 4 + r;
        acc[g][r] = b2f(xgp[m * 1024 + g * Hn + U]);
      }
    }

    if (s > 0) {
      for (;;) {
        int v = (lane < 32)
                  ? __hip_atomic_load(&myflags[lane], __ATOMIC_RELAXED, __HIP_MEMORY_SCOPE_AGENT)
                  : s;
        if (__all(v >= s)) break;
        __builtin_amdgcn_s_sleep(1);
      }
      // h_{s-1} loads: relaxed agent atomics (coherent point, no fence needed)
      const unsigned long long* hq = (const unsigned long long*)myhb;
      const int pbase = ((s - 1) & 1) * 2048 + mrow * 64;  // u64 units
#pragma unroll
      for (int ki = 0; ki < 8; ++ki) {
        const int idx = pbase + ki * 8 + quad * 2;
        unsigned long long q0 = __hip_atomic_load(hq + idx, __ATOMIC_RELAXED, __HIP_MEMORY_SCOPE_AGENT);
        unsigned long long q1 = __hip_atomic_load(hq + idx + 1, __ATOMIC_RELAXED, __HIP_MEMORY_SCOPE_AGENT);
        union { unsigned long long q[2]; short8 s8; } u;
        u.q[0] = q0; u.q[1] = q1;
#pragma unroll
        for (int g = 0; g < 4; ++g)
          acc[g] = __builtin_amdgcn_mfma_f32_16x16x32_bf16(u.s8, bfh[ki][g], acc[g], 0, 0, 0);
      }
    }

    // gates + state + h broadcast (paired-lane packed u32 atomic stores)
    unsigned int* hw32 = (unsigned int*)(myhb + (s & 1) * (Bn * Hn));
#pragma unroll
    for (int r = 0; r < 4; ++r) {
      const int m = mh * 16 + quad * 4 + r;
      float ig = sigx(acc[0][r]), fg = sigx(acc[1][r]);
      float gg = tanhx(acc[2][r]), og = sigx(acc[3][r]);
      float cv = fg * c_st[r] + ig * gg;
      c_st[r] = cv;
      float hv = og * tanhx(cv);
      unsigned short hb16 = f2b(hv);
      int pk = __shfl_xor((int)hb16, 1);
      if (!(lane & 1)) {
        unsigned int pv = (unsigned)hb16 | ((unsigned)pk << 16);
        __hip_atomic_store(hw32 + m * 128 + (U >> 1), pv, __ATOMIC_RELAXED, __HIP_MEMORY_SCOPE_AGENT);
      }
      if constexpr (!LAYER1) {
        h0out[((size_t)m * Tn + t) * 512 + scan * Hn + U] = hb16;
      } else {
        dout[((size_t)m * Tn + t) * 512 + scan * Hn + U] = hv;
      }
    }

    // order h stores before flag store: bare vmcnt drain, no cache maintenance
    asm volatile("s_waitcnt vmcnt(0)" ::: "memory");
    if (lane == 0)
      __hip_atomic_store(&myflags[slot], s + 1, __ATOMIC_RELAXED, __HIP_MEMORY_SCOPE_AGENT);
  }
}

extern "C" void kernel_launch(void* const* d_in, const int* in_sizes, int n_in,
                              void* d_out, int out_size, void* d_ws, size_t ws_size,
                              hipStream_t stream) {
  (void)in_sizes; (void)n_in; (void)out_size; (void)ws_size;
  const float* x      = (const float*)d_in[0];
  const float* Wih_f0 = (const float*)d_in[1];
  const float* Whh_f0 = (const float*)d_in[2];
  const float* b_f0   = (const float*)d_in[3];
  const float* Wih_r0 = (const float*)d_in[4];
  const float* Whh_r0 = (const float*)d_in[5];
  const float* b_r0   = (const float*)d_in[6];
  const float* Wih_f1 = (const float*)d_in[7];
  const float* Whh_f1 = (const float*)d_in[8];
  const float* b_f1   = (const float*)d_in[9];
  const float* Wih_r1 = (const float*)d_in[10];
  const float* Whh_r1 = (const float*)d_in[11];
  const float* b_r1   = (const float*)d_in[12];

  char* ws = (char*)d_ws;
  unsigned short* xgbuf = (unsigned short*)ws;                 // 268,435,456 B
  size_t off = (size_t)2 * Tn * Bn * 1024 * sizeof(unsigned short);
  unsigned short* h0out = (unsigned short*)(ws + off);         // 67,108,864 B
  off += (size_t)Bn * Tn * 512 * sizeof(unsigned short);
  unsigned short* hbufA = (unsigned short*)(ws + off); off += 2 * 2 * Bn * Hn * 2;
  unsigned short* hbufB = (unsigned short*)(ws + off); off += 2 * 2 * Bn * Hn * 2;
  int* flagsA = (int*)(ws + off);                              // 64 ints
  int* flagsB = flagsA + 64;

  hipMemsetAsync(flagsA, 0, 512, stream);  // both flag arrays -> 0

  dim3 blk(256);
  // layer 0
  xg_gemm<256, true><<<dim3(4096), blk, 0, stream>>>(
      (const void*)x, Wih_f0, b_f0, Wih_r0, b_r0, xgbuf);
  lstm_scan<false><<<dim3(16), blk, 0, stream>>>(
      xgbuf, Whh_f0, Whh_r0, hbufA, flagsA, h0out, (float*)nullptr);
  // layer 1
  xg_gemm<512, false><<<dim3(4096), blk, 0, stream>>>(
      (const void*)h0out, Wih_f1, b_f1, Wih_r1, b_r1, xgbuf);
  lstm_scan<true><<<dim3(16), blk, 0, stream>>>(
      xgbuf, Whh_f1, Whh_r1, hbufB, flagsB, (unsigned short*)nullptr, (float*)d_out);
}